// Round 2
// baseline (206.472 us; speedup 1.0000x reference)
//
#include <hip/hip_runtime.h>

#define LSEQ 512
#define BATCH 256
#define DIM 256
#define WMAX 128
#define ROW4 (BATCH * DIM / 4)   // feats row stride in float4 units
#define BD4 (DIM / 4)            // batch stride in float4 units
#define WPB 16                   // words per block
#define WPW 4                    // words per wave (WPB / 4 waves)

// Fused kernel: one block per (word-group, batch). Each block recomputes its
// batch's run-start positions from word_ids/amask in LDS (ids are sorted and
// densified -> run start = boundary), windowed to the WPB words it owns, then
// streams the char rows and writes the means. WPB=16 amortizes the meta phase
// (6KB load + barriers, redundant per batch) over 4x more pool work than the
// WPB=4 version, and gives each wave 4 sequential words -> longer-lived waves,
// deeper load pipelining, 4x fewer blocks (2048 = ~resident capacity).
__global__ __launch_bounds__(256) void fused_pool_kernel(
    const float* __restrict__ feats,     // [L, B, D]
    const int* __restrict__ word_ids,    // [B, L]
    const int* __restrict__ amask,       // [B, L]
    float* __restrict__ out)             // [W, B, D] then masks [W, B]
{
    const int b    = blockIdx.x & (BATCH - 1);
    const int wg   = blockIdx.x >> 8;
    const int t    = threadIdx.x;
    const int lane = t & 63;
    const int wi   = t >> 6;
    const int w0   = wg * WPB;

    __shared__ int sids[LSEQ];
    __shared__ int spart[4];
    __shared__ int sstart[WPB + 1];

    // --- meta phase: load ids row into LDS, reduce attention mask ---
    int msum = 0;
    if (t < 128) {
        ((int4*)sids)[t] = ((const int4*)(word_ids + b * LSEQ))[t];
    } else {
        int4 m = ((const int4*)(amask + b * LSEQ))[t - 128];
        msum = m.x + m.y + m.z + m.w;
    }
    #pragma unroll
    for (int off = 32; off; off >>= 1) msum += __shfl_down(msum, off, 64);
    if (lane == 0) spart[wi] = msum;
    __syncthreads();

    const int char_num = spart[0] + spart[1] + spart[2] + spart[3] - 2;
    int pend = 1 + char_num;             // valid positions: [1, pend)
    if (pend < 1) pend = 1;
    if (pend > LSEQ) pend = LSEQ;

    if (t <= WPB) sstart[t] = pend;      // sentinel: empty/tail words
    __syncthreads();

    // run boundaries, windowed to words [w0, w0+WPB]
    for (int p = 1 + t; p < pend; p += 256) {
        const int id = sids[p];
        if ((p == 1 || id != sids[p - 1]) && id >= w0 && id <= w0 + WPB)
            sstart[id - w0] = p;
    }
    if (t == 0 && wg == 0) sstart[0] = 1;   // word 0 (only t==0 ever writes it)
    __syncthreads();

    // masks output (once per batch, by the wg==0 blocks)
    if (wg == 0 && t < WMAX) {
        const int word_num = sids[LSEQ - 1] + 1;   // sorted -> last is max
        out[(size_t)WMAX * BATCH * DIM + (size_t)t * BATCH + b] =
            (t < word_num) ? 1.0f : 0.0f;
    }

    // --- pool phase: each wave owns WPW consecutive words ---
    const float4* __restrict__ f4 = (const float4*)feats;
    const int boff  = b * BD4 + lane;
    const int wbase = wi * WPW;

    #pragma unroll
    for (int k = 0; k < WPW; ++k) {
        const int s0 = sstart[wbase + k];
        const int s1 = sstart[wbase + k + 1];
        const int c  = s1 - s0;          // >= 0; 0 for empty/padded words

        float4 acc = make_float4(0.f, 0.f, 0.f, 0.f);
        for (int i = 0; i < c; i += 8) {
            const int n = c - i;         // wave-uniform
            float4 v[8];
            #pragma unroll
            for (int j = 0; j < 8; j++) {
                if (j < n) v[j] = f4[(size_t)(s0 + i + j) * ROW4 + boff];
            }
            #pragma unroll
            for (int j = 0; j < 8; j++) {
                if (j < n) {
                    acc.x += v[j].x; acc.y += v[j].y;
                    acc.z += v[j].z; acc.w += v[j].w;
                }
            }
        }

        const float inv = 1.0f / (float)(c > 0 ? c : 1);
        ((float4*)out)[(size_t)(w0 + wbase + k) * ROW4 + boff] =
            make_float4(acc.x * inv, acc.y * inv, acc.z * inv, acc.w * inv);
    }
}

extern "C" void kernel_launch(void* const* d_in, const int* in_sizes, int n_in,
                              void* d_out, int out_size, void* d_ws, size_t ws_size,
                              hipStream_t stream) {
    const float* char_feats = (const float*)d_in[0];
    const int* word_ids     = (const int*)d_in[1];
    const int* amask        = (const int*)d_in[2];
    float* out              = (float*)d_out;
    (void)d_ws; (void)ws_size;   // workspace intentionally untouched

    fused_pool_kernel<<<(WMAX / WPB) * BATCH, 256, 0, stream>>>(
        char_feats, word_ids, amask, out);
}

// Round 6
// 191.349 us; speedup vs baseline: 1.0790x; 1.0790x over previous
//
#include <hip/hip_runtime.h>

#define LSEQ 512
#define BATCH 256
#define DIM 256
#define WMAX 128
#define ROW4 (BATCH * DIM / 4)   // feats row stride in float4 units
#define BD4 (DIM / 4)            // batch stride in float4 units
#define WPB 4                    // words per block (one per wave) — best measured config

// Native clang vector type: __builtin_nontemporal_load/store require a
// pointer to scalar or native vector — HIP's float4 class wrapper is invalid.
typedef float f4v __attribute__((ext_vector_type(4)));

// Fused kernel: one block per (word-group, batch). Each block recomputes its
// batch's run-start positions from word_ids/amask in LDS (ids are sorted and
// densified -> run start = boundary), windowed to the WPB words it owns, then
// streams the char rows and writes the means.
// feats/out are single-touch streams -> nontemporal load/store (nt flag)
// to avoid L2/L3 allocation churn on 168 MB of zero-reuse traffic.
// Grid order is WORD-GROUP-MAJOR: blockIdx = wg*BATCH + b, so resident blocks
// cover all batches of a narrow row window (page/L2 locality on feats).
// WPB=4 (8192 blocks, ~4 residency rounds) beat WPB=16 (one round) — the
// extra rounds provide dynamic load balancing for Poisson(4) run lengths.
__global__ __launch_bounds__(256) void fused_pool_kernel(
    const float* __restrict__ feats,     // [L, B, D]
    const int* __restrict__ word_ids,    // [B, L]
    const int* __restrict__ amask,       // [B, L]
    float* __restrict__ out)             // [W, B, D] then masks [W, B]
{
    const int b    = blockIdx.x & (BATCH - 1);
    const int wg   = blockIdx.x >> 8;
    const int t    = threadIdx.x;
    const int lane = t & 63;
    const int wi   = t >> 6;
    const int w0   = wg * WPB;

    __shared__ int sids[LSEQ];
    __shared__ int spart[4];
    __shared__ int sstart[WPB + 1];

    // --- meta phase: load ids row into LDS, reduce attention mask ---
    int msum = 0;
    if (t < 128) {
        ((int4*)sids)[t] = ((const int4*)(word_ids + b * LSEQ))[t];
    } else {
        int4 m = ((const int4*)(amask + b * LSEQ))[t - 128];
        msum = m.x + m.y + m.z + m.w;
    }
    #pragma unroll
    for (int off = 32; off; off >>= 1) msum += __shfl_down(msum, off, 64);
    if (lane == 0) spart[wi] = msum;
    __syncthreads();

    const int char_num = spart[0] + spart[1] + spart[2] + spart[3] - 2;
    int pend = 1 + char_num;             // valid positions: [1, pend)
    if (pend < 1) pend = 1;
    if (pend > LSEQ) pend = LSEQ;

    if (t <= WPB) sstart[t] = pend;      // sentinel: empty/tail words
    __syncthreads();

    // run boundaries, windowed to words [w0, w0+WPB]
    for (int p = 1 + t; p < pend; p += 256) {
        const int id = sids[p];
        if ((p == 1 || id != sids[p - 1]) && id >= w0 && id <= w0 + WPB)
            sstart[id - w0] = p;
    }
    if (t == 0 && wg == 0) sstart[0] = 1;   // word 0 (only t==0 ever writes it)
    __syncthreads();

    // masks output (once per batch, by the wg==0 blocks)
    if (wg == 0 && t < WMAX) {
        const int word_num = sids[LSEQ - 1] + 1;   // sorted -> last is max
        out[(size_t)WMAX * BATCH * DIM + (size_t)t * BATCH + b] =
            (t < word_num) ? 1.0f : 0.0f;
    }

    // --- pool phase: one wave per (word, batch) ---
    const int s0 = sstart[wi];
    const int s1 = sstart[wi + 1];
    const int c  = s1 - s0;              // >= 0; 0 for empty/padded words

    const f4v* __restrict__ f4 = (const f4v*)feats;
    const int boff = b * BD4 + lane;
    const int w = w0 + wi;

    f4v acc = (f4v)(0.0f);
    for (int i = 0; i < c; i += 8) {
        const int n = c - i;             // wave-uniform
        f4v v[8];
        #pragma unroll
        for (int j = 0; j < 8; j++) {
            if (j < n) v[j] = __builtin_nontemporal_load(
                                  &f4[(size_t)(s0 + i + j) * ROW4 + boff]);
        }
        #pragma unroll
        for (int j = 0; j < 8; j++) {
            if (j < n) acc += v[j];
        }
    }

    const float inv = 1.0f / (float)(c > 0 ? c : 1);
    const f4v res = acc * inv;
    __builtin_nontemporal_store(res, &((f4v*)out)[(size_t)w * ROW4 + boff]);
}

extern "C" void kernel_launch(void* const* d_in, const int* in_sizes, int n_in,
                              void* d_out, int out_size, void* d_ws, size_t ws_size,
                              hipStream_t stream) {
    const float* char_feats = (const float*)d_in[0];
    const int* word_ids     = (const int*)d_in[1];
    const int* amask        = (const int*)d_in[2];
    float* out              = (float*)d_out;
    (void)d_ws; (void)ws_size;   // workspace intentionally untouched

    fused_pool_kernel<<<(WMAX / WPB) * BATCH, 256, 0, stream>>>(
        char_feats, word_ids, amask, out);
}